// Round 11
// baseline (27.999 us; speedup 1.0000x reference)
//
#include <hip/hip_runtime.h>
#include <float.h>

#define BATCH 8
#define NPTS 4096
#define BLK 256
#define THALF 1024            // targets per block (one quarter)
#define NH 4                  // target quarters

typedef __attribute__((ext_vector_type(8))) short short8;      // 8 bf16
typedef __attribute__((ext_vector_type(16))) float floatx16;   // 32x32 MFMA acc

union U4S8 { uint4 u; short8 s; };

// round-to-nearest-even f32 -> bf16 bits
__device__ inline unsigned short f2bf(float f) {
    unsigned u = __float_as_uint(f);
    return (unsigned short)((u + 0x7FFFu + ((u >> 16) & 1u)) >> 16);
}
__device__ inline float bf2f(unsigned short h) {
    return __uint_as_float(((unsigned)h) << 16);
}
__device__ inline unsigned flag_token(int i) {
    return 0x9E3779B9u * (unsigned)(i + 7);   // never 0xAAAAAAAA poison
}

// ---------------------------------------------------------------------------
// Main kernel: grid = 1024 blocks = (dirb(16), rowgroup(16), quarter(4)).
// SINGLE CHANGE vs round 10: __launch_bounds__(BLK) with NO min-wave clause.
// Round 10's (BLK,4) capped VGPRs at 128 while live state is ~140+ (32 rmn +
// 16 zero + 64 in-flight MFMA accs + 8 afrag + 16 ping-pong + temps) ->
// forced scratch spills in the inner loop (~5x slowdown pattern). Uncapped,
// the compiler allocates ~160-190 VGPR -> 0 spills at 2-3 waves/SIMD; LDS is
// only 16 KB so residency stays >= 2 blocks/CU.
// Numerics identical to rounds 7-10 (absmax 0.0).
// ---------------------------------------------------------------------------
__global__ __launch_bounds__(BLK) void chamfer_partial(
        const float* __restrict__ ori, const float* __restrict__ adv,
        float* __restrict__ rfin) {
    __shared__ uint4 sm[THALF];   // 16 KB

    int bx = blockIdx.x;               // 0..1023
    int half = bx & (NH - 1);
    int rowgroup = (bx >> 2) & 15;
    int dirb = bx >> 6;                // 0..15
    int b = dirb & 7;
    int dir = dirb >> 3;

    const float* qsrc = dir ? adv : ori;   // dir0: ori->adv, dir1: adv->ori
    const float* tsrc = dir ? ori : adv;

    // ---- stage this quarter's 1024 targets, packed hi/lo, into LDS ----
    {
        const float* tx = tsrc + (b * 3 + 0) * NPTS;
        const float* ty = tsrc + (b * 3 + 1) * NPTS;
        const float* tz = tsrc + (b * 3 + 2) * NPTS;
        #pragma unroll
        for (int i = 0; i < THALF / BLK; ++i) {
            int p = threadIdx.x + i * BLK;
            int m = half * THALF + p;
            float x = tx[m], y = ty[m], z = tz[m];
            float n2 = fmaf(x, x, fmaf(y, y, z * z));
            unsigned short hx = f2bf(x), hy = f2bf(y), hz = f2bf(z);
            unsigned short lx = f2bf(x - bf2f(hx));
            unsigned short ly = f2bf(y - bf2f(hy));
            unsigned short lz = f2bf(z - bf2f(hz));
            unsigned short h2 = f2bf(n2);
            unsigned short l2 = f2bf(n2 - bf2f(h2));
            uint4 u;
            u.x = (unsigned)hx | ((unsigned)hy << 16);
            u.y = (unsigned)hz | ((unsigned)lx << 16);
            u.z = (unsigned)ly | ((unsigned)lz << 16);
            u.w = (unsigned)h2 | ((unsigned)l2 << 16);
            sm[p] = u;
        }
    }

    // ---- per-wave A fragments for 2 bands of 32 rows ----
    int w = threadIdx.x >> 6;          // wave 0..3
    int l = threadIdx.x & 63;
    int lrow = l & 31;
    int kh = l >> 5;

    short8 afrag[2];
    #pragma unroll
    for (int bi = 0; bi < 2; ++bi) {
        int q = rowgroup * 256 + (w * 2 + bi) * 32 + lrow;
        float x = qsrc[(b * 3 + 0) * NPTS + q];
        float y = qsrc[(b * 3 + 1) * NPTS + q];
        float z = qsrc[(b * 3 + 2) * NPTS + q];
        float n2 = fmaf(x, x, fmaf(y, y, z * z));
        unsigned short hx = f2bf(x), hy = f2bf(y), hz = f2bf(z);
        unsigned short lx = f2bf(x - bf2f(hx));
        unsigned short ly = f2bf(y - bf2f(hy));
        unsigned short lz = f2bf(z - bf2f(hz));
        unsigned short h2 = f2bf(n2);
        unsigned short l2 = f2bf(n2 - bf2f(h2));
        unsigned short mhx = f2bf(-2.0f * bf2f(hx));
        unsigned short mhy = f2bf(-2.0f * bf2f(hy));
        unsigned short mhz = f2bf(-2.0f * bf2f(hz));
        unsigned short mlx = f2bf(-2.0f * bf2f(lx));
        unsigned short mly = f2bf(-2.0f * bf2f(ly));
        unsigned short mlz = f2bf(-2.0f * bf2f(lz));
        const unsigned short one = 0x3F80;
        union { unsigned short us[8]; short8 s8; } A;
        if (kh == 0) {
            A.us[0] = mhx; A.us[1] = mhy; A.us[2] = mhz;
            A.us[3] = mhx; A.us[4] = mhy; A.us[5] = mhz;
            A.us[6] = one; A.us[7] = one;
        } else {
            A.us[0] = mlx; A.us[1] = mly; A.us[2] = mlz;
            A.us[3] = h2;  A.us[4] = l2;
            A.us[5] = 0;   A.us[6] = 0;   A.us[7] = 0;
        }
        afrag[bi] = A.s8;
    }
    __syncthreads();

    floatx16 zero, rmn0, rmn1;
    #pragma unroll
    for (int r = 0; r < 16; ++r) { zero[r] = 0.0f; rmn0[r] = FLT_MAX; rmn1[r] = FLT_MAX; }

    bool hi = (kh == 1);
    int col = lrow;

#define PROCESS2(r0, r1)                                                       \
    {                                                                          \
        U4S8 f0, f1;                                                           \
        f0.u.x = (r0).x;                                                       \
        f0.u.y = hi ? (((r0).y & 0xFFFFu) | 0x3F800000u) : (r0).y;             \
        f0.u.z = hi ? 0x00003F80u : (r0).z;                                    \
        f0.u.w = hi ? 0u : (r0).w;                                             \
        f1.u.x = (r1).x;                                                       \
        f1.u.y = hi ? (((r1).y & 0xFFFFu) | 0x3F800000u) : (r1).y;             \
        f1.u.z = hi ? 0x00003F80u : (r1).z;                                    \
        f1.u.w = hi ? 0u : (r1).w;                                             \
        floatx16 a0 = __builtin_amdgcn_mfma_f32_32x32x16_bf16(afrag[0], f0.s, zero, 0, 0, 0); \
        floatx16 a1 = __builtin_amdgcn_mfma_f32_32x32x16_bf16(afrag[0], f1.s, zero, 0, 0, 0); \
        _Pragma("unroll")                                                      \
        for (int r = 0; r < 16; ++r)                                           \
            rmn0[r] = fminf(fminf(rmn0[r], a0[r]), a1[r]);                     \
        floatx16 c0 = __builtin_amdgcn_mfma_f32_32x32x16_bf16(afrag[1], f0.s, zero, 0, 0, 0); \
        floatx16 c1 = __builtin_amdgcn_mfma_f32_32x32x16_bf16(afrag[1], f1.s, zero, 0, 0, 0); \
        _Pragma("unroll")                                                      \
        for (int r = 0; r < 16; ++r)                                           \
            rmn1[r] = fminf(fminf(rmn1[r], c0[r]), c1[r]);                     \
    }

    // ping-pong pipelined loop over this quarter's 32 col-tiles (2 per iter)
    {
        uint4 r0 = sm[col], r1 = sm[32 + col];
        #pragma unroll 1
        for (int ct = 0; ct < 30; ct += 2) {
            uint4 p0 = sm[(ct + 2) * 32 + col];
            uint4 p1 = sm[(ct + 3) * 32 + col];
            PROCESS2(r0, r1);
            r0 = p0; r1 = p1;
        }
        PROCESS2(r0, r1);
    }
#undef PROCESS2

    // ---- butterfly row-min over the 32 cols; write partial row-mins ----
    #pragma unroll
    for (int r = 0; r < 16; ++r) {
        float v0 = rmn0[r], v1 = rmn1[r];
        #pragma unroll
        for (int m = 1; m <= 16; m <<= 1) {
            v0 = fminf(v0, __shfl_xor(v0, m));
            v1 = fminf(v1, __shfl_xor(v1, m));
        }
        rmn0[r] = v0; rmn1[r] = v1;
    }
    if (lrow == 0) {
        // C/D row = (r&3) + 8*(r>>2) + 4*kh (verified m74/m101, rounds 7-10)
        float* base = rfin + (((size_t)(dirb * NH + half)) << 12)
                    + rowgroup * 256 + kh * 4;
        float* d0 = base + (w * 2 + 0) * 32;
        float* d1 = base + (w * 2 + 1) * 32;
        #pragma unroll
        for (int r = 0; r < 16; ++r) {
            int off = (r & 3) + 8 * (r >> 2);
            d0[off] = rmn0[r];
            d1[off] = rmn1[r];
        }
    }
}

// ---------------------------------------------------------------------------
// Combine: 16 blocks (one per dirb). Each thread: 16 rows, min over the 4
// quarter-partials, clamp >=0, fixed-order sum -> bsum[dirb] + token flag.
// Block 0 then spins on the 16 flags and finalizes to out[0]. 16 blocks are
// trivially co-resident. Replays write bit-identical values -> deterministic.
// ---------------------------------------------------------------------------
__global__ __launch_bounds__(BLK) void combine_kernel(
        const float* __restrict__ rfin, float* __restrict__ bsum,
        unsigned* __restrict__ flags, float* __restrict__ out) {
    __shared__ float ws[4];
    __shared__ float sh[16];
    int dirb = blockIdx.x;
    const float* p = rfin + (((size_t)dirb * NH) << 12);
    float s = 0.0f;
    #pragma unroll
    for (int k = 0; k < 16; ++k) {
        int row = k * BLK + threadIdx.x;
        float m = fminf(fminf(p[row], p[(1 << 12) + row]),
                        fminf(p[(2 << 12) + row], p[(3 << 12) + row]));
        s += fmaxf(m, 0.0f);
    }
    for (int off = 32; off > 0; off >>= 1) s += __shfl_down(s, off);
    int wid = threadIdx.x >> 6, lane = threadIdx.x & 63;
    if (lane == 0) ws[wid] = s;
    __syncthreads();
    if (threadIdx.x == 0) {
        float t = ws[0] + ws[1] + ws[2] + ws[3];
        atomicExch((unsigned*)(bsum + dirb), __float_as_uint(t));
        __threadfence();
        atomicExch(flags + dirb, flag_token(dirb));
    }

    if (dirb == 0) {
        __syncthreads();
        int t = threadIdx.x;
        if (t < 16) {
            unsigned want = flag_token(t);
            while (atomicAdd(flags + t, 0u) != want) {
                __builtin_amdgcn_s_sleep(1);
            }
            sh[t] = __uint_as_float(atomicAdd((unsigned*)(bsum + t), 0u));
        }
        __syncthreads();
        if (t == 0) {
            float acc = 0.0f;
            #pragma unroll
            for (int bb = 0; bb < BATCH; ++bb)
                acc += fmaxf(sh[bb], sh[8 + bb]);
            out[0] = acc * (1.0f / (float)NPTS) * (1.0f / (float)BATCH);
        }
    }
}

extern "C" void kernel_launch(void* const* d_in, const int* in_sizes, int n_in,
                              void* d_out, int out_size, void* d_ws, size_t ws_size,
                              hipStream_t stream) {
    const float* ori = (const float*)d_in[0];
    const float* adv = (const float*)d_in[1];
    float* out = (float*)d_out;

    // ws: rfin[16 dirb][4 quarter][4096 row] floats (1 MB) | bsum[16] | flags[16]
    float* rfin = (float*)d_ws;
    float* bsum = rfin + (size_t)16 * NH * NPTS;
    unsigned* flags = (unsigned*)(bsum + 16);

    chamfer_partial<<<16 * 16 * NH, BLK, 0, stream>>>(ori, adv, rfin);
    combine_kernel<<<16, BLK, 0, stream>>>(rfin, bsum, flags, out);
}

// Round 12
// 25.551 us; speedup vs baseline: 1.0958x; 1.0958x over previous
//
#include <hip/hip_runtime.h>
#include <float.h>

#define BATCH 8
#define NPTS 4096
#define BLK 256
#define THALF 1024            // targets per block (one quarter)
#define NH 4                  // target quarters

typedef __attribute__((ext_vector_type(8))) short short8;      // 8 bf16
typedef __attribute__((ext_vector_type(16))) float floatx16;   // 32x32 MFMA acc

union U4S8 { uint4 u; short8 s; };

// round-to-nearest-even f32 -> bf16 bits
__device__ inline unsigned short f2bf(float f) {
    unsigned u = __float_as_uint(f);
    return (unsigned short)((u + 0x7FFFu + ((u >> 16) & 1u)) >> 16);
}
__device__ inline float bf2f(unsigned short h) {
    return __uint_as_float(((unsigned)h) << 16);
}
__device__ inline unsigned flag_token(int i) {
    return 0x9E3779B9u * (unsigned)(i + 7);   // never 0xAAAAAAAA poison
}

// ---------------------------------------------------------------------------
// Main kernel: grid = 1024 = (dirb(16), rowgroup(16), quarter(4)), 4 blocks/CU
// (round 10's best config: __launch_bounds__(256,4), VGPR<=128).
// CHANGE vs round 10: staging precomputes BOTH K=16 B-fragment variants into
// LDS (fr[kh][t], 32 KB) so the inner loop is pure ds_read_b128 -> MFMA ->
// min3 -- no per-iter cndmask fragment rebuild (-16 VALU/iter, shorter
// dependency chain). kh planes 16 KB apart: lanes l and l+32 alias banks
// 2-way (free, m136).
// Numerics identical to rounds 7-11 (absmax 0.0): K=16 hi/lo bf16 encoding
// folds |q|^2 + |t|^2 - 2q.t into one mfma_f32_32x32x16_bf16.
// ---------------------------------------------------------------------------
__global__ __launch_bounds__(BLK, 4) void chamfer_partial(
        const float* __restrict__ ori, const float* __restrict__ adv,
        float* __restrict__ rfin) {
    __shared__ uint4 fr[2 * THALF];   // 32 KB: fr[kh*THALF + t]

    int bx = blockIdx.x;               // 0..1023
    int half = bx & (NH - 1);
    int rowgroup = (bx >> 2) & 15;
    int dirb = bx >> 6;                // 0..15
    int b = dirb & 7;
    int dir = dirb >> 3;

    const float* qsrc = dir ? adv : ori;   // dir0: ori->adv, dir1: adv->ori
    const float* tsrc = dir ? ori : adv;

    // ---- stage this quarter's 1024 targets as BOTH B-frag variants ----
    {
        const float* tx = tsrc + (b * 3 + 0) * NPTS;
        const float* ty = tsrc + (b * 3 + 1) * NPTS;
        const float* tz = tsrc + (b * 3 + 2) * NPTS;
        #pragma unroll
        for (int i = 0; i < THALF / BLK; ++i) {
            int p = threadIdx.x + i * BLK;
            int m = half * THALF + p;
            float x = tx[m], y = ty[m], z = tz[m];
            float n2 = fmaf(x, x, fmaf(y, y, z * z));
            unsigned short hx = f2bf(x), hy = f2bf(y), hz = f2bf(z);
            unsigned short lx = f2bf(x - bf2f(hx));
            unsigned short ly = f2bf(y - bf2f(hy));
            unsigned short lz = f2bf(z - bf2f(hz));
            unsigned short h2 = f2bf(n2);
            unsigned short l2 = f2bf(n2 - bf2f(h2));
            // variant kh=0: B rows 0..7 = [thi.x,thi.y,thi.z, tlo.x,tlo.y,tlo.z, n2h,n2l]
            uint4 v0;
            v0.x = (unsigned)hx | ((unsigned)hy << 16);
            v0.y = (unsigned)hz | ((unsigned)lx << 16);
            v0.z = (unsigned)ly | ((unsigned)lz << 16);
            v0.w = (unsigned)h2 | ((unsigned)l2 << 16);
            // variant kh=1: B rows 8..15 = [thi.x,thi.y,thi.z, 1, 1, 0,0,0]
            uint4 v1;
            v1.x = v0.x;
            v1.y = (unsigned)hz | (0x3F80u << 16);
            v1.z = 0x00003F80u;
            v1.w = 0u;
            fr[p] = v0;
            fr[THALF + p] = v1;
        }
    }

    // ---- per-wave A fragments for 2 bands of 32 rows ----
    int w = threadIdx.x >> 6;          // wave 0..3
    int l = threadIdx.x & 63;
    int lrow = l & 31;
    int kh = l >> 5;

    short8 afrag[2];
    #pragma unroll
    for (int bi = 0; bi < 2; ++bi) {
        int q = rowgroup * 256 + (w * 2 + bi) * 32 + lrow;
        float x = qsrc[(b * 3 + 0) * NPTS + q];
        float y = qsrc[(b * 3 + 1) * NPTS + q];
        float z = qsrc[(b * 3 + 2) * NPTS + q];
        float n2 = fmaf(x, x, fmaf(y, y, z * z));
        unsigned short hx = f2bf(x), hy = f2bf(y), hz = f2bf(z);
        unsigned short lx = f2bf(x - bf2f(hx));
        unsigned short ly = f2bf(y - bf2f(hy));
        unsigned short lz = f2bf(z - bf2f(hz));
        unsigned short h2 = f2bf(n2);
        unsigned short l2 = f2bf(n2 - bf2f(h2));
        unsigned short mhx = f2bf(-2.0f * bf2f(hx));
        unsigned short mhy = f2bf(-2.0f * bf2f(hy));
        unsigned short mhz = f2bf(-2.0f * bf2f(hz));
        unsigned short mlx = f2bf(-2.0f * bf2f(lx));
        unsigned short mly = f2bf(-2.0f * bf2f(ly));
        unsigned short mlz = f2bf(-2.0f * bf2f(lz));
        const unsigned short one = 0x3F80;
        union { unsigned short us[8]; short8 s8; } A;
        if (kh == 0) {
            A.us[0] = mhx; A.us[1] = mhy; A.us[2] = mhz;
            A.us[3] = mhx; A.us[4] = mhy; A.us[5] = mhz;
            A.us[6] = one; A.us[7] = one;
        } else {
            A.us[0] = mlx; A.us[1] = mly; A.us[2] = mlz;
            A.us[3] = h2;  A.us[4] = l2;
            A.us[5] = 0;   A.us[6] = 0;   A.us[7] = 0;
        }
        afrag[bi] = A.s8;
    }
    __syncthreads();

    floatx16 zero, rmn0, rmn1;
    #pragma unroll
    for (int r = 0; r < 16; ++r) { zero[r] = 0.0f; rmn0[r] = FLT_MAX; rmn1[r] = FLT_MAX; }

    // per-lane frag pointer: plane kh, column lrow
    const uint4* tp = fr + kh * THALF + lrow;

#define PROCESS2(f0u, f1u)                                                     \
    {                                                                          \
        U4S8 f0, f1; f0.u = (f0u); f1.u = (f1u);                               \
        floatx16 a0 = __builtin_amdgcn_mfma_f32_32x32x16_bf16(afrag[0], f0.s, zero, 0, 0, 0); \
        floatx16 a1 = __builtin_amdgcn_mfma_f32_32x32x16_bf16(afrag[0], f1.s, zero, 0, 0, 0); \
        _Pragma("unroll")                                                      \
        for (int r = 0; r < 16; ++r)                                           \
            rmn0[r] = fminf(fminf(rmn0[r], a0[r]), a1[r]);                     \
        floatx16 c0 = __builtin_amdgcn_mfma_f32_32x32x16_bf16(afrag[1], f0.s, zero, 0, 0, 0); \
        floatx16 c1 = __builtin_amdgcn_mfma_f32_32x32x16_bf16(afrag[1], f1.s, zero, 0, 0, 0); \
        _Pragma("unroll")                                                      \
        for (int r = 0; r < 16; ++r)                                           \
            rmn1[r] = fminf(fminf(rmn1[r], c0[r]), c1[r]);                     \
    }

    // ping-pong pipelined loop over this quarter's 32 col-tiles (2 per iter)
    {
        uint4 r0 = tp[0], r1 = tp[32];
        #pragma unroll 1
        for (int ct = 0; ct < 30; ct += 2) {
            uint4 p0 = tp[(ct + 2) * 32];
            uint4 p1 = tp[(ct + 3) * 32];
            PROCESS2(r0, r1);
            r0 = p0; r1 = p1;
        }
        PROCESS2(r0, r1);
    }
#undef PROCESS2

    // ---- butterfly row-min over the 32 cols; write partial row-mins ----
    #pragma unroll
    for (int r = 0; r < 16; ++r) {
        float v0 = rmn0[r], v1 = rmn1[r];
        #pragma unroll
        for (int m = 1; m <= 16; m <<= 1) {
            v0 = fminf(v0, __shfl_xor(v0, m));
            v1 = fminf(v1, __shfl_xor(v1, m));
        }
        rmn0[r] = v0; rmn1[r] = v1;
    }
    if (lrow == 0) {
        // C/D row = (r&3) + 8*(r>>2) + 4*kh (verified m74/m101, rounds 7-11)
        float* base = rfin + (((size_t)(dirb * NH + half)) << 12)
                    + rowgroup * 256 + kh * 4;
        float* d0 = base + (w * 2 + 0) * 32;
        float* d1 = base + (w * 2 + 1) * 32;
        #pragma unroll
        for (int r = 0; r < 16; ++r) {
            int off = (r & 3) + 8 * (r >> 2);
            d0[off] = rmn0[r];
            d1[off] = rmn1[r];
        }
    }
}

// ---------------------------------------------------------------------------
// Combine: 256 blocks = (dirb(16), rowslice(16)). Each thread: 1 row, min
// over 4 quarter-partials, clamp >=0; block reduces 256 rows -> pb[cb] +
// token flag. Block 0 then spins on the 256 flags (one per thread) and
// finalizes to out[0] (round-9-proven gather). All replays write
// bit-identical values -> deterministic.
// ---------------------------------------------------------------------------
__global__ __launch_bounds__(BLK) void combine_kernel(
        const float* __restrict__ rfin, float* __restrict__ pb,
        unsigned* __restrict__ flags, float* __restrict__ out) {
    __shared__ float ws[4];
    __shared__ float sh[256 + 16];
    int cb = blockIdx.x;               // dirb*16 + rowslice
    int dirb = cb >> 4;
    int rs = cb & 15;
    const float* p = rfin + (((size_t)dirb * NH) << 12) + rs * 256;
    int row = threadIdx.x;
    float m = fminf(fminf(p[row], p[(1 << 12) + row]),
                    fminf(p[(2 << 12) + row], p[(3 << 12) + row]));
    float s = fmaxf(m, 0.0f);
    for (int off = 32; off > 0; off >>= 1) s += __shfl_down(s, off);
    int wid = threadIdx.x >> 6, lane = threadIdx.x & 63;
    if (lane == 0) ws[wid] = s;
    __syncthreads();
    if (threadIdx.x == 0) {
        float t = ws[0] + ws[1] + ws[2] + ws[3];
        atomicExch((unsigned*)(pb + cb), __float_as_uint(t));
        __threadfence();
        atomicExch(flags + cb, flag_token(cb));
    }

    if (cb == 0) {
        __syncthreads();
        int t = threadIdx.x;               // 256 threads, one flag each
        unsigned want = flag_token(t);
        while (atomicAdd(flags + t, 0u) != want) {
            __builtin_amdgcn_s_sleep(1);
        }
        sh[t] = __uint_as_float(atomicAdd((unsigned*)(pb + t), 0u));
        __syncthreads();
        if (t < 16) {
            float acc = 0.0f;
            #pragma unroll
            for (int c = 0; c < 16; ++c) acc += sh[t * 16 + c];
            sh[256 + t] = acc;
        }
        __syncthreads();
        if (t == 0) {
            float acc = 0.0f;
            #pragma unroll
            for (int bb = 0; bb < BATCH; ++bb)
                acc += fmaxf(sh[256 + bb], sh[256 + 8 + bb]);
            out[0] = acc * (1.0f / (float)NPTS) * (1.0f / (float)BATCH);
        }
    }
}

extern "C" void kernel_launch(void* const* d_in, const int* in_sizes, int n_in,
                              void* d_out, int out_size, void* d_ws, size_t ws_size,
                              hipStream_t stream) {
    const float* ori = (const float*)d_in[0];
    const float* adv = (const float*)d_in[1];
    float* out = (float*)d_out;

    // ws: rfin[16 dirb][4 quarter][4096 row] floats (1 MB) | pb[256] | flags[256]
    float* rfin = (float*)d_ws;
    float* pb = rfin + (size_t)16 * NH * NPTS;
    unsigned* flags = (unsigned*)(pb + 256);

    chamfer_partial<<<16 * 16 * NH, BLK, 0, stream>>>(ori, adv, rfin);
    combine_kernel<<<256, BLK, 0, stream>>>(rfin, pb, flags, out);
}